// Round 1
// baseline (487.654 us; speedup 1.0000x reference)
//
#include <hip/hip_runtime.h>
#include <hip/hip_bf16.h>

#define NN 384
#define NP (NN*NN)      // 147456 positions
#define CC 128
#define LDP 136         // padded LDS leading dim (16B-aligned rows, breaks bank conflicts)

typedef __attribute__((ext_vector_type(8))) short bf16x8;
typedef __attribute__((ext_vector_type(4))) float f32x4;
typedef __attribute__((ext_vector_type(8))) unsigned short u16x8;

__device__ __forceinline__ unsigned short f2bf(float f){
  unsigned int u = __float_as_uint(f);
  u += 0x7FFFu + ((u >> 16) & 1u);     // round-to-nearest-even
  return (unsigned short)(u >> 16);
}
__device__ __forceinline__ float bf2f(unsigned short h){
  return __uint_as_float(((unsigned int)h) << 16);
}
__device__ __forceinline__ float sigm(float x){ return 1.f / (1.f + __expf(-x)); }

// stage f32 W[k][n] (128x128 row-major) -> LDS transposed bf16 w_lds[n*LDP+k]
__device__ __forceinline__ void stage_w_T(const float* __restrict__ W, unsigned short* w_lds, int tid){
  for (int i = tid; i < CC*CC; i += 256){
    int k = i >> 7, n = i & 127;
    w_lds[n*LDP + k] = f2bf(W[i]);
  }
}

// acc[mr][nr] += A(128 rows x K=128, row-major stride LDP) @ W (w_lds[n][k])
// wave computes rows [wave*32, wave*32+32) x all 128 cols
__device__ __forceinline__ void gemm_128(const unsigned short* a_lds, const unsigned short* w_lds,
                                         int wave, int lane, f32x4 acc[2][8]){
  const int l16 = lane & 15;
  const int lk  = (lane >> 4) * 8;
  const int row0 = wave * 32;
  #pragma unroll
  for (int kc = 0; kc < 4; ++kc){
    bf16x8 af[2], bfr[8];
    #pragma unroll
    for (int mr = 0; mr < 2; ++mr)
      af[mr] = *(const bf16x8*)&a_lds[(row0 + mr*16 + l16)*LDP + kc*32 + lk];
    #pragma unroll
    for (int nr = 0; nr < 8; ++nr)
      bfr[nr] = *(const bf16x8*)&w_lds[(nr*16 + l16)*LDP + kc*32 + lk];
    #pragma unroll
    for (int mr = 0; mr < 2; ++mr)
      #pragma unroll
      for (int nr = 0; nr < 8; ++nr)
        acc[mr][nr] = __builtin_amdgcn_mfma_f32_16x16x32_bf16(af[mr], bfr[nr], acc[mr][nr], 0, 0, 0);
  }
}

// ---------------- K1: LN(z) + 5 projections + nonlinearities ----------------
__global__ __launch_bounds__(256) void k1(
    const float* __restrict__ z, const float* __restrict__ mask,
    const float* __restrict__ lnw, const float* __restrict__ lnb,
    const float* __restrict__ wag, const float* __restrict__ bag,
    const float* __restrict__ wap, const float* __restrict__ bap,
    const float* __restrict__ wbg, const float* __restrict__ bbg,
    const float* __restrict__ wbp, const float* __restrict__ bbp,
    const float* __restrict__ wg,  const float* __restrict__ bgt,
    unsigned short* __restrict__ At, unsigned short* __restrict__ Bt,
    unsigned short* __restrict__ G)
{
  __shared__ unsigned short zn[CC*LDP];   // [pos][c] bf16
  __shared__ unsigned short wl[CC*LDP];   // weights [n][k] bf16; reused as out-stage
  const int tid = threadIdx.x;
  const int wave = tid >> 6, lane = tid & 63;
  const int posbase = blockIdx.x * 128;

  // LN over channels: one wave per position, lane covers c=lane and c=lane+64
  float lw0 = lnw[lane], lw1 = lnw[lane+64];
  float lb0 = lnb[lane], lb1 = lnb[lane+64];
  for (int it = 0; it < 32; ++it){
    int pl = wave*32 + it;
    size_t base = (size_t)(posbase + pl) * CC;
    float v0 = z[base + lane], v1 = z[base + lane + 64];
    float s = v0 + v1, q = v0*v0 + v1*v1;
    #pragma unroll
    for (int off = 32; off; off >>= 1){ s += __shfl_xor(s, off); q += __shfl_xor(q, off); }
    float mean = s * (1.f/128.f);
    float rstd = rsqrtf(q*(1.f/128.f) - mean*mean + 1e-5f);
    zn[pl*LDP + lane]      = f2bf((v0 - mean)*rstd*lw0 + lb0);
    zn[pl*LDP + lane + 64] = f2bf((v1 - mean)*rstd*lw1 + lb1);
  }
  __syncthreads();

  // a and b branches: m * sigmoid(zn@Wg + bg) * (zn@Wp + bp), stored [c][pos]
  for (int pr = 0; pr < 2; ++pr){
    const float* Wg  = pr ? wbg : wag;
    const float* Wp  = pr ? wbp : wap;
    const float* Bg_ = pr ? bbg : bag;
    const float* Bp_ = pr ? bbp : bap;
    unsigned short* dst = pr ? Bt : At;

    stage_w_T(Wg, wl, tid);
    __syncthreads();
    f32x4 accg[2][8] = {};
    gemm_128(zn, wl, wave, lane, accg);
    __syncthreads();
    stage_w_T(Wp, wl, tid);
    __syncthreads();
    f32x4 accp[2][8] = {};
    gemm_128(zn, wl, wave, lane, accp);
    __syncthreads();          // all waves done with weights; reuse wl as out-stage [c][pos]

    const int l16 = lane & 15;
    #pragma unroll
    for (int nr = 0; nr < 8; ++nr){
      int c = nr*16 + l16;
      float bgv = Bg_[c], bpv = Bp_[c];
      #pragma unroll
      for (int mr = 0; mr < 2; ++mr){
        #pragma unroll
        for (int r = 0; r < 4; ++r){
          int pl = wave*32 + mr*16 + (lane>>4)*4 + r;   // C/D: col=lane&15, row=(lane>>4)*4+r
          float m = mask[posbase + pl];
          float v = m * sigm(accg[mr][nr][r] + bgv) * (accp[mr][nr][r] + bpv);
          wl[c*LDP + pl] = f2bf(v);
        }
      }
    }
    __syncthreads();
    for (int i = tid; i < CC*16; i += 256){   // coalesced [c][pos] -> global
      int c = i >> 4, seg = i & 15;
      u16x8 v = *(const u16x8*)&wl[c*LDP + seg*8];
      *(u16x8*)&dst[(size_t)c*NP + posbase + seg*8] = v;
    }
    __syncthreads();
  }

  // gate g = sigmoid(zn@wg + bg), layout [pos][c]
  stage_w_T(wg, wl, tid);
  __syncthreads();
  f32x4 accG[2][8] = {};
  gemm_128(zn, wl, wave, lane, accG);
  __syncthreads();
  {
    const int l16 = lane & 15;
    #pragma unroll
    for (int nr = 0; nr < 8; ++nr){
      int c = nr*16 + l16;
      float bgv = bgt[c];
      #pragma unroll
      for (int mr = 0; mr < 2; ++mr)
        #pragma unroll
        for (int r = 0; r < 4; ++r){
          int pl = wave*32 + mr*16 + (lane>>4)*4 + r;
          wl[pl*LDP + c] = f2bf(sigm(accG[mr][nr][r] + bgv));
        }
    }
  }
  __syncthreads();
  for (int i = tid; i < CC*16; i += 256){
    int pl = i >> 4, seg = i & 15;
    u16x8 v = *(const u16x8*)&wl[pl*LDP + seg*8];
    *(u16x8*)&G[((size_t)(posbase + pl))*CC + seg*8] = v;
  }
}

// ---------------- K2: per-channel triangle GEMM  X_c = A_c * B_c^T ----------------
__global__ __launch_bounds__(256) void k2(const unsigned short* __restrict__ At,
                                          const unsigned short* __restrict__ Bt,
                                          unsigned short* __restrict__ Xt)
{
  __shared__ unsigned short As[128*64];   // [row][k] bf16, linear
  __shared__ unsigned short Bs[128*64];
  const int c  = blockIdx.y;
  const int ti = blockIdx.x / 3, tj = blockIdx.x % 3;
  const int tid = threadIdx.x, wave = tid >> 6, lane = tid & 63;
  const unsigned short* Ag = At + (size_t)c*NP + (size_t)(ti*128)*NN;
  const unsigned short* Bg = Bt + (size_t)c*NP + (size_t)(tj*128)*NN;
  const int l16 = lane & 15, lk = (lane >> 4)*8, row0 = wave*32;
  f32x4 acc[2][8] = {};
  for (int k0 = 0; k0 < NN; k0 += 64){
    __syncthreads();
    for (int i = tid; i < 1024; i += 256){
      int row = i >> 3, seg = i & 7;
      *(u16x8*)&As[row*64 + seg*8] = *(const u16x8*)&Ag[(size_t)row*NN + k0 + seg*8];
      *(u16x8*)&Bs[row*64 + seg*8] = *(const u16x8*)&Bg[(size_t)row*NN + k0 + seg*8];
    }
    __syncthreads();
    #pragma unroll
    for (int kc = 0; kc < 2; ++kc){
      bf16x8 af[2], bfr[8];
      #pragma unroll
      for (int mr = 0; mr < 2; ++mr)
        af[mr] = *(const bf16x8*)&As[(row0 + mr*16 + l16)*64 + kc*32 + lk];
      #pragma unroll
      for (int nr = 0; nr < 8; ++nr)
        bfr[nr] = *(const bf16x8*)&Bs[(nr*16 + l16)*64 + kc*32 + lk];
      #pragma unroll
      for (int mr = 0; mr < 2; ++mr)
        #pragma unroll
        for (int nr = 0; nr < 8; ++nr)
          acc[mr][nr] = __builtin_amdgcn_mfma_f32_16x16x32_bf16(af[mr], bfr[nr], acc[mr][nr], 0,0,0);
    }
  }
  size_t base = (size_t)c*NP + (size_t)(ti*128)*NN + tj*128;
  #pragma unroll
  for (int mr = 0; mr < 2; ++mr)
    #pragma unroll
    for (int nr = 0; nr < 8; ++nr)
      #pragma unroll
      for (int r = 0; r < 4; ++r){
        int row = row0 + mr*16 + (lane>>4)*4 + r;
        int col = nr*16 + l16;
        Xt[base + (size_t)row*NN + col] = f2bf(acc[mr][nr][r]);
      }
}

// ---------------- K3: LN(x) + x@w_z + b_z, times gate ----------------
__global__ __launch_bounds__(256) void k3(const unsigned short* __restrict__ Xt,
                                          const unsigned short* __restrict__ G,
                                          const float* __restrict__ lnw, const float* __restrict__ lnb,
                                          const float* __restrict__ wz, const float* __restrict__ bz,
                                          float* __restrict__ out)
{
  __shared__ unsigned short xc[CC*LDP];  // [c][pos] bf16 (as stored by K2)
  __shared__ unsigned short yl[CC*LDP];  // [pos][c] bf16 (post-LN)
  __shared__ unsigned short wl[CC*LDP];  // w_z transposed [n][k]
  const int tid = threadIdx.x, wave = tid >> 6, lane = tid & 63;
  const int posbase = blockIdx.x * 128;

  for (int i = tid; i < CC*16; i += 256){
    int cch = i >> 4, seg = i & 15;
    *(u16x8*)&xc[cch*LDP + seg*8] = *(const u16x8*)&Xt[(size_t)cch*NP + posbase + seg*8];
  }
  stage_w_T(wz, wl, tid);
  __syncthreads();

  float lw0 = lnw[lane], lw1 = lnw[lane+64];
  float lb0 = lnb[lane], lb1 = lnb[lane+64];
  for (int it = 0; it < 32; ++it){
    int pl = wave*32 + it;
    float v0 = bf2f(xc[lane*LDP + pl]);
    float v1 = bf2f(xc[(lane+64)*LDP + pl]);
    float s = v0 + v1, q = v0*v0 + v1*v1;
    #pragma unroll
    for (int off = 32; off; off >>= 1){ s += __shfl_xor(s, off); q += __shfl_xor(q, off); }
    float mean = s*(1.f/128.f);
    float rstd = rsqrtf(q*(1.f/128.f) - mean*mean + 1e-5f);
    yl[pl*LDP + lane]    = f2bf((v0 - mean)*rstd*lw0 + lb0);
    yl[pl*LDP + lane+64] = f2bf((v1 - mean)*rstd*lw1 + lb1);
  }
  __syncthreads();

  f32x4 acc[2][8] = {};
  gemm_128(yl, wl, wave, lane, acc);

  const int l16 = lane & 15;
  #pragma unroll
  for (int nr = 0; nr < 8; ++nr){
    int cch = nr*16 + l16;
    float bzv = bz[cch];
    #pragma unroll
    for (int mr = 0; mr < 2; ++mr)
      #pragma unroll
      for (int r = 0; r < 4; ++r){
        int pl = wave*32 + mr*16 + (lane>>4)*4 + r;
        size_t o = (size_t)(posbase + pl)*CC + cch;
        out[o] = (acc[mr][nr][r] + bzv) * bf2f(G[o]);
      }
  }
}

extern "C" void kernel_launch(void* const* d_in, const int* in_sizes, int n_in,
                              void* d_out, int out_size, void* d_ws, size_t ws_size,
                              hipStream_t stream)
{
  const float* z    = (const float*)d_in[0];
  const float* mask = (const float*)d_in[1];
  const float* lniw = (const float*)d_in[2];
  const float* lnib = (const float*)d_in[3];
  const float* wag  = (const float*)d_in[4];
  const float* bag  = (const float*)d_in[5];
  const float* wap  = (const float*)d_in[6];
  const float* bap  = (const float*)d_in[7];
  const float* wbg  = (const float*)d_in[8];
  const float* bbg  = (const float*)d_in[9];
  const float* wbp  = (const float*)d_in[10];
  const float* bbp  = (const float*)d_in[11];
  const float* lnow = (const float*)d_in[12];
  const float* lnob = (const float*)d_in[13];
  const float* wz   = (const float*)d_in[14];
  const float* bz   = (const float*)d_in[15];
  const float* wg   = (const float*)d_in[16];
  const float* bg   = (const float*)d_in[17];
  float* out = (float*)d_out;

  unsigned short* At = (unsigned short*)d_ws;            // [c][pos] bf16, 37.75 MB
  unsigned short* Bt = At + (size_t)CC*NP;               // [c][pos]
  unsigned short* G  = Bt + (size_t)CC*NP;               // [pos][c]
  unsigned short* Xt = G  + (size_t)CC*NP;               // [c][pos]

  k1<<<dim3(NP/128), 256, 0, stream>>>(z, mask, lniw, lnib, wag, bag, wap, bap,
                                       wbg, bbg, wbp, bbp, wg, bg, At, Bt, G);
  k2<<<dim3(9, CC), 256, 0, stream>>>(At, Bt, Xt);
  k3<<<dim3(NP/128), 256, 0, stream>>>(Xt, G, lnow, lnob, wz, bz, out);
}

// Round 2
// 400.701 us; speedup vs baseline: 1.2170x; 1.2170x over previous
//
#include <hip/hip_runtime.h>
#include <hip/hip_bf16.h>

#define NN 384
#define NP (NN*NN)      // 147456 positions
#define CC 128

typedef __attribute__((ext_vector_type(8))) short bf16x8;
typedef __attribute__((ext_vector_type(4))) float f32x4;
typedef __attribute__((ext_vector_type(8))) unsigned short u16x8;
typedef __attribute__((ext_vector_type(4))) unsigned short u16x4;

// XOR swizzle: col in shorts, rows of 128 shorts (16 granules of 16B)
#define SW16(row, col) ((col) ^ (((row)&15)<<3))
// rows of 64 shorts (8 granules)
#define SW8(row, col)  ((col) ^ (((row)&7)<<3))

__device__ __forceinline__ unsigned short f2bf(float f){
  unsigned int u = __float_as_uint(f);
  u += 0x7FFFu + ((u >> 16) & 1u);     // round-to-nearest-even
  return (unsigned short)(u >> 16);
}
__device__ __forceinline__ float bf2f(unsigned short h){
  return __uint_as_float(((unsigned int)h) << 16);
}
__device__ __forceinline__ float sigm(float x){ return 1.f / (1.f + __expf(-x)); }

// ---------------- k0: convert 6 f32 weight mats [k][n] -> bf16 Wt[m][n][k] ----------------
__global__ __launch_bounds__(256) void k0(const float* __restrict__ w0, const float* __restrict__ w1,
                                          const float* __restrict__ w2, const float* __restrict__ w3,
                                          const float* __restrict__ w4, const float* __restrict__ w5,
                                          unsigned short* __restrict__ Wt)
{
  __shared__ unsigned short t[CC*CC];
  const float* W = blockIdx.x==0?w0: blockIdx.x==1?w1: blockIdx.x==2?w2:
                   blockIdx.x==3?w3: blockIdx.x==4?w4: w5;
  unsigned short* o = Wt + blockIdx.x*CC*CC;
  for (int i = threadIdx.x; i < CC*CC; i += 256){
    int k = i >> 7, n = i & 127;
    t[n*CC + SW16(n, k)] = f2bf(W[i]);          // coalesced read, transposed swizzled write
  }
  __syncthreads();
  for (int i = threadIdx.x; i < CC*16; i += 256){
    int n = i >> 4, g = i & 15;
    *(u16x8*)&o[n*CC + g*8] = *(const u16x8*)&t[n*CC + SW16(n, g*8)];
  }
}

// ---------------- k1: LN(z) + 5 projections + nonlinearities ----------------
// a/b GEMMs are operand-SWAPPED: D[c][pos] = Wt_x[c][k] * zn[pos][k]^T, so the
// [c][pos] global layout stores directly from accumulators (no LDS transpose).
__global__ __launch_bounds__(256) void k1(
    const float* __restrict__ z, const float* __restrict__ mask,
    const float* __restrict__ lnw, const float* __restrict__ lnb,
    const float* __restrict__ bag, const float* __restrict__ bap,
    const float* __restrict__ bbg, const float* __restrict__ bbp,
    const float* __restrict__ bgt,
    const unsigned short* __restrict__ Wt,
    unsigned short* __restrict__ At, unsigned short* __restrict__ Bt,
    unsigned short* __restrict__ G)
{
  __shared__ unsigned short zn[CC*CC];   // [pos][k] bf16, swizzled
  const int tid = threadIdx.x, wave = tid>>6, lane = tid&63;
  const int l16 = lane&15, lg = lane>>4;
  const int posbase = blockIdx.x*128;

  { // LN: 2 positions per wave-iter, float4 loads, 32-lane shuffle reduce
    const int lh = lane&31, hh = lane>>5;
    const float4 lw4 = *(const float4*)&lnw[4*lh];
    const float4 lb4 = *(const float4*)&lnb[4*lh];
    for (int it = 0; it < 16; ++it){
      int pl = wave*32 + it*2 + hh;
      float4 v = *(const float4*)&z[(size_t)(posbase+pl)*CC + 4*lh];
      float s = v.x+v.y+v.z+v.w;
      float q = v.x*v.x+v.y*v.y+v.z*v.z+v.w*v.w;
      #pragma unroll
      for (int off = 16; off; off >>= 1){ s += __shfl_xor(s, off); q += __shfl_xor(q, off); }
      float mean = s*(1.f/128.f);
      float rstd = rsqrtf(q*(1.f/128.f) - mean*mean + 1e-5f);
      u16x4 o;
      o[0] = f2bf((v.x-mean)*rstd*lw4.x + lb4.x);
      o[1] = f2bf((v.y-mean)*rstd*lw4.y + lb4.y);
      o[2] = f2bf((v.z-mean)*rstd*lw4.z + lb4.z);
      o[3] = f2bf((v.w-mean)*rstd*lw4.w + lb4.w);
      *(u16x4*)&zn[pl*CC + SW16(pl, 4*lh)] = o;
    }
  }
  __syncthreads();   // the only barrier in k1

  // a and b branches: dual GEMM (shared zn B-frags), split into two pos-halves
  #pragma unroll 1
  for (int pr = 0; pr < 2; ++pr){
    const unsigned short* Wg = Wt + (pr*2+0)*CC*CC;
    const unsigned short* Wp = Wt + (pr*2+1)*CC*CC;
    const float* Bg_ = pr ? bbg : bag;
    const float* Bp_ = pr ? bbp : bap;
    unsigned short* dst = pr ? Bt : At;
    float4 bg4[2], bp4[2];
    #pragma unroll
    for (int ma = 0; ma < 2; ++ma){
      int cb = wave*32 + ma*16 + lg*4;
      bg4[ma] = *(const float4*)&Bg_[cb];
      bp4[ma] = *(const float4*)&Bp_[cb];
    }
    #pragma unroll 1
    for (int half = 0; half < 2; ++half){
      f32x4 ag[2][4] = {}; f32x4 ap[2][4] = {};
      #pragma unroll
      for (int kc = 0; kc < 4; ++kc){
        const int kb = kc*32 + lg*8;
        bf16x8 bz[4], wgf[2], wpf[2];
        #pragma unroll
        for (int nb = 0; nb < 4; ++nb){
          int pos = half*64 + nb*16 + l16;
          bz[nb] = *(const bf16x8*)&zn[pos*CC + SW16(pos, kb)];
        }
        #pragma unroll
        for (int ma = 0; ma < 2; ++ma){
          int c = wave*32 + ma*16 + l16;
          wgf[ma] = *(const bf16x8*)&Wg[c*CC + kb];
          wpf[ma] = *(const bf16x8*)&Wp[c*CC + kb];
        }
        #pragma unroll
        for (int ma = 0; ma < 2; ++ma)
          #pragma unroll
          for (int nb = 0; nb < 4; ++nb){
            ag[ma][nb] = __builtin_amdgcn_mfma_f32_16x16x32_bf16(wgf[ma], bz[nb], ag[ma][nb], 0,0,0);
            ap[ma][nb] = __builtin_amdgcn_mfma_f32_16x16x32_bf16(wpf[ma], bz[nb], ap[ma][nb], 0,0,0);
          }
      }
      #pragma unroll
      for (int nb = 0; nb < 4; ++nb){
        int pos = posbase + half*64 + nb*16 + l16;
        float m = mask[pos];
        #pragma unroll
        for (int ma = 0; ma < 2; ++ma){
          int cb = wave*32 + ma*16 + lg*4;
          #pragma unroll
          for (int r = 0; r < 4; ++r){
            float bgv = r==0?bg4[ma].x : r==1?bg4[ma].y : r==2?bg4[ma].z : bg4[ma].w;
            float bpv = r==0?bp4[ma].x : r==1?bp4[ma].y : r==2?bp4[ma].z : bp4[ma].w;
            float v = m * sigm(ag[ma][nb][r] + bgv) * (ap[ma][nb][r] + bpv);
            dst[(size_t)(cb + r)*NP + pos] = f2bf(v);
          }
        }
      }
    }
  }

  // gate g = sigmoid(zn@wg + bg): unswapped, D[pos][c] -> G[pos][c]
  {
    const unsigned short* Wgt = Wt + 4*CC*CC;
    f32x4 acc[2][8] = {};
    #pragma unroll
    for (int kc = 0; kc < 4; ++kc){
      const int kb = kc*32 + lg*8;
      bf16x8 az[2], wf[8];
      #pragma unroll
      for (int ma = 0; ma < 2; ++ma){
        int pos = wave*32 + ma*16 + l16;
        az[ma] = *(const bf16x8*)&zn[pos*CC + SW16(pos, kb)];
      }
      #pragma unroll
      for (int nr = 0; nr < 8; ++nr)
        wf[nr] = *(const bf16x8*)&Wgt[(nr*16+l16)*CC + kb];
      #pragma unroll
      for (int ma = 0; ma < 2; ++ma)
        #pragma unroll
        for (int nr = 0; nr < 8; ++nr)
          acc[ma][nr] = __builtin_amdgcn_mfma_f32_16x16x32_bf16(az[ma], wf[nr], acc[ma][nr], 0,0,0);
    }
    #pragma unroll
    for (int nr = 0; nr < 8; ++nr){
      int c = nr*16 + l16;
      float bv = bgt[c];
      #pragma unroll
      for (int ma = 0; ma < 2; ++ma)
        #pragma unroll
        for (int r = 0; r < 4; ++r){
          int pos = posbase + wave*32 + ma*16 + lg*4 + r;
          G[(size_t)pos*CC + c] = f2bf(sigm(acc[ma][nr][r] + bv));
        }
    }
  }
}

// ---------------- k2: per-channel triangle GEMM  X_c = A_c * B_c^T ----------------
__global__ __launch_bounds__(256) void k2(const unsigned short* __restrict__ At,
                                          const unsigned short* __restrict__ Bt,
                                          unsigned short* __restrict__ Xt)
{
  __shared__ unsigned short As[128*64];   // [row][k] bf16, swizzled
  __shared__ unsigned short Bs[128*64];
  const int c  = blockIdx.y;
  const int ti = blockIdx.x / 3, tj = blockIdx.x % 3;
  const int tid = threadIdx.x, wave = tid >> 6, lane = tid & 63;
  const int l16 = lane & 15, lg = lane >> 4;
  const unsigned short* Ag = At + (size_t)c*NP + (size_t)(ti*128)*NN;
  const unsigned short* Bg = Bt + (size_t)c*NP + (size_t)(tj*128)*NN;
  f32x4 acc[2][8] = {};
  for (int k0 = 0; k0 < NN; k0 += 64){
    __syncthreads();
    #pragma unroll
    for (int it = 0; it < 4; ++it){       // reg-stage, swizzled LDS writes (conflict-free)
      int i = tid + it*256;
      int row = i >> 3, g = i & 7;
      u16x8 va = *(const u16x8*)&Ag[(size_t)row*NN + k0 + g*8];
      u16x8 vb = *(const u16x8*)&Bg[(size_t)row*NN + k0 + g*8];
      *(u16x8*)&As[row*64 + SW8(row, g*8)] = va;
      *(u16x8*)&Bs[row*64 + SW8(row, g*8)] = vb;
    }
    __syncthreads();
    #pragma unroll
    for (int kc = 0; kc < 2; ++kc){
      const int kb = kc*32 + lg*8;
      bf16x8 af[2], bfr[8];
      #pragma unroll
      for (int ma = 0; ma < 2; ++ma){
        int row = wave*32 + ma*16 + l16;
        af[ma] = *(const bf16x8*)&As[row*64 + SW8(row, kb)];
      }
      #pragma unroll
      for (int nr = 0; nr < 8; ++nr){
        int row = nr*16 + l16;
        bfr[nr] = *(const bf16x8*)&Bs[row*64 + SW8(row, kb)];
      }
      #pragma unroll
      for (int ma = 0; ma < 2; ++ma)
        #pragma unroll
        for (int nr = 0; nr < 8; ++nr)
          acc[ma][nr] = __builtin_amdgcn_mfma_f32_16x16x32_bf16(af[ma], bfr[nr], acc[ma][nr], 0,0,0);
    }
  }
  size_t base = (size_t)c*NP + (size_t)(ti*128)*NN + tj*128;
  #pragma unroll
  for (int ma = 0; ma < 2; ++ma)
    #pragma unroll
    for (int nr = 0; nr < 8; ++nr)
      #pragma unroll
      for (int r = 0; r < 4; ++r){
        int row = wave*32 + ma*16 + lg*4 + r;
        int col = nr*16 + l16;
        Xt[base + (size_t)row*NN + col] = f2bf(acc[ma][nr][r]);
      }
}

// ---------------- k3: LN(x) over c + x@w_z + b_z, times gate ----------------
__global__ __launch_bounds__(256) void k3(const unsigned short* __restrict__ Xt,
                                          const unsigned short* __restrict__ G,
                                          const float* __restrict__ lnw, const float* __restrict__ lnb,
                                          const unsigned short* __restrict__ Wzt, const float* __restrict__ bz,
                                          float* __restrict__ out)
{
  __shared__ unsigned short xc[CC*CC];   // [c][pos] bf16, swizzled
  __shared__ unsigned short yt[CC*CC];   // [pos][c] bf16, swizzled (post-LN, transposed)
  __shared__ float mu[CC], rs[CC];
  const int tid = threadIdx.x, wave = tid>>6, lane = tid&63;
  const int l16 = lane&15, lg = lane>>4;
  const int posbase = blockIdx.x*128;

  #pragma unroll
  for (int it = 0; it < 8; ++it){        // stage xc (coalesced reads, swizzled writes)
    int i = tid + it*256;
    int cc = i >> 4, g = i & 15;
    u16x8 v = *(const u16x8*)&Xt[(size_t)cc*NP + posbase + g*8];
    *(u16x8*)&xc[cc*CC + SW16(cc, g*8)] = v;
  }
  __syncthreads();

  { // column-parallel LN stats: lane owns 4 positions, iterates 64 channels; no serial per-pos loop
    const int lh = lane&31, hh = lane>>5;
    f32x4 s4 = {0,0,0,0}, q4 = {0,0,0,0};
    for (int ci = 0; ci < 64; ++ci){
      int cc = hh*64 + ci;
      u16x4 v = *(const u16x4*)&xc[cc*CC + SW16(cc, 4*lh)];
      #pragma unroll
      for (int j = 0; j < 4; ++j){
        float f = bf2f(v[j]);
        s4[j] += f; q4[j] += f*f;
      }
    }
    #pragma unroll
    for (int j = 0; j < 4; ++j){ s4[j] += __shfl_xor(s4[j], 32); q4[j] += __shfl_xor(q4[j], 32); }
    if (hh == 0){
      f32x4 m4, r4;
      #pragma unroll
      for (int j = 0; j < 4; ++j){
        float mean = s4[j]*(1.f/128.f);
        m4[j] = mean;
        r4[j] = rsqrtf(q4[j]*(1.f/128.f) - mean*mean + 1e-5f);
      }
      *(f32x4*)&mu[4*lh] = m4;
      *(f32x4*)&rs[4*lh] = r4;
    }
  }
  __syncthreads();

  #pragma unroll
  for (int it = 0; it < 8; ++it){        // normalize + transpose: contiguous LDS row writes
    int i = tid + it*256;
    int cc = i & 127, g = i >> 7;
    u16x8 v = *(const u16x8*)&xc[cc*CC + SW16(cc, g*8)];
    float lw = lnw[cc], lb = lnb[cc];
    #pragma unroll
    for (int j = 0; j < 8; ++j){
      int pos = g*8 + j;
      float f = (bf2f(v[j]) - mu[pos]) * rs[pos] * lw + lb;
      yt[pos*CC + SW16(pos, cc)] = f2bf(f);
    }
  }
  __syncthreads();

  f32x4 acc[2][8] = {};
  #pragma unroll
  for (int kc = 0; kc < 4; ++kc){
    const int kb = kc*32 + lg*8;
    bf16x8 af[2], wf[8];
    #pragma unroll
    for (int ma = 0; ma < 2; ++ma){
      int pos = wave*32 + ma*16 + l16;
      af[ma] = *(const bf16x8*)&yt[pos*CC + SW16(pos, kb)];
    }
    #pragma unroll
    for (int nr = 0; nr < 8; ++nr)
      wf[nr] = *(const bf16x8*)&Wzt[(nr*16+l16)*CC + kb];
    #pragma unroll
    for (int ma = 0; ma < 2; ++ma)
      #pragma unroll
      for (int nr = 0; nr < 8; ++nr)
        acc[ma][nr] = __builtin_amdgcn_mfma_f32_16x16x32_bf16(af[ma], wf[nr], acc[ma][nr], 0,0,0);
  }
  #pragma unroll
  for (int nr = 0; nr < 8; ++nr){
    int cch = nr*16 + l16;
    float bzv = bz[cch];
    #pragma unroll
    for (int ma = 0; ma < 2; ++ma)
      #pragma unroll
      for (int r = 0; r < 4; ++r){
        int pos = posbase + wave*32 + ma*16 + lg*4 + r;
        size_t o = (size_t)pos*CC + cch;
        out[o] = (acc[ma][nr][r] + bzv) * bf2f(G[o]);
      }
  }
}

extern "C" void kernel_launch(void* const* d_in, const int* in_sizes, int n_in,
                              void* d_out, int out_size, void* d_ws, size_t ws_size,
                              hipStream_t stream)
{
  const float* z    = (const float*)d_in[0];
  const float* mask = (const float*)d_in[1];
  const float* lniw = (const float*)d_in[2];
  const float* lnib = (const float*)d_in[3];
  const float* wag  = (const float*)d_in[4];
  const float* bag  = (const float*)d_in[5];
  const float* wap  = (const float*)d_in[6];
  const float* bap  = (const float*)d_in[7];
  const float* wbg  = (const float*)d_in[8];
  const float* bbg  = (const float*)d_in[9];
  const float* wbp  = (const float*)d_in[10];
  const float* bbp  = (const float*)d_in[11];
  const float* lnow = (const float*)d_in[12];
  const float* lnob = (const float*)d_in[13];
  const float* wz   = (const float*)d_in[14];
  const float* bz   = (const float*)d_in[15];
  const float* wg   = (const float*)d_in[16];
  const float* bg   = (const float*)d_in[17];
  float* out = (float*)d_out;

  unsigned short* Wt = (unsigned short*)d_ws;            // 6 x 128x128 bf16 = 384 KB
  unsigned short* At = Wt + 6*CC*CC;                     // [c][pos] bf16, 37.75 MB
  unsigned short* Bt = At + (size_t)CC*NP;               // [c][pos]
  unsigned short* G  = Bt + (size_t)CC*NP;               // [pos][c]
  unsigned short* Xt = G  + (size_t)CC*NP;               // [c][pos]

  k0<<<6, 256, 0, stream>>>(wag, wap, wbg, wbp, wg, wz, Wt);
  k1<<<NP/128, 256, 0, stream>>>(z, mask, lniw, lnib, bag, bap, bbg, bbp, bg, Wt, At, Bt, G);
  k2<<<dim3(9, CC), 256, 0, stream>>>(At, Bt, Xt);
  k3<<<NP/128, 256, 0, stream>>>(Xt, G, lnow, lnob, Wt + 5*CC*CC, bz, out);
}

// Round 3
// 393.945 us; speedup vs baseline: 1.2379x; 1.0171x over previous
//
#include <hip/hip_runtime.h>
#include <hip/hip_bf16.h>

#define NN 384
#define NP (NN*NN)      // 147456 positions
#define CC 128

typedef __attribute__((ext_vector_type(8))) short bf16x8;
typedef __attribute__((ext_vector_type(4))) float f32x4;
typedef __attribute__((ext_vector_type(8))) unsigned short u16x8;
typedef __attribute__((ext_vector_type(4))) unsigned short u16x4;

// XOR swizzle: col in shorts, rows of 128 shorts (16 granules of 16B)
#define SW16(row, col) ((col) ^ (((row)&15)<<3))
// rows of 64 shorts (8 granules)
#define SW8(row, col)  ((col) ^ (((row)&7)<<3))

typedef const __attribute__((address_space(1))) unsigned int GLu32;
typedef __attribute__((address_space(3))) unsigned int LDu32;
__device__ __forceinline__ void gload_lds16(const void* g, void* l){
  __builtin_amdgcn_global_load_lds((GLu32*)g, (LDu32*)l, 16, 0, 0);
}

__device__ __forceinline__ unsigned short f2bf(float f){
  unsigned int u = __float_as_uint(f);
  u += 0x7FFFu + ((u >> 16) & 1u);     // round-to-nearest-even
  return (unsigned short)(u >> 16);
}
__device__ __forceinline__ float bf2f(unsigned short h){
  return __uint_as_float(((unsigned int)h) << 16);
}
__device__ __forceinline__ float sigm(float x){ return 1.f / (1.f + __expf(-x)); }

// ---------------- k0: weight prep ----------------
// blocks 0..5: f32 W[k][n] -> bf16 Wt[m][n][k] (block 5 = wz scaled by lnow)
// block 6: wsum[c] = sum_k lnow[k]*wz[k][c]; bzp[c] = bz[c] + sum_k lnob[k]*wz[k][c]
__global__ __launch_bounds__(256) void k0(const float* __restrict__ w0, const float* __restrict__ w1,
                                          const float* __restrict__ w2, const float* __restrict__ w3,
                                          const float* __restrict__ w4, const float* __restrict__ w5,
                                          const float* __restrict__ lnow, const float* __restrict__ lnob,
                                          const float* __restrict__ bz,
                                          unsigned short* __restrict__ Wt,
                                          float* __restrict__ wsum, float* __restrict__ bzp)
{
  if (blockIdx.x == 6){
    __shared__ float p1[256], p2[256];
    int c = threadIdx.x & 127, half = threadIdx.x >> 7;
    float s1 = 0.f, s2 = 0.f;
    #pragma unroll 8
    for (int k = half*64; k < half*64 + 64; ++k){
      float w = w5[k*CC + c];
      s1 += lnow[k]*w; s2 += lnob[k]*w;
    }
    p1[threadIdx.x] = s1; p2[threadIdx.x] = s2;
    __syncthreads();
    if (half == 0){
      wsum[c] = s1 + p1[128 + c];
      bzp[c]  = bz[c] + s2 + p2[128 + c];
    }
    return;
  }
  __shared__ unsigned short t[CC*CC];
  const float* W = blockIdx.x==0?w0: blockIdx.x==1?w1: blockIdx.x==2?w2:
                   blockIdx.x==3?w3: blockIdx.x==4?w4: w5;
  const bool scale = (blockIdx.x == 5);
  unsigned short* o = Wt + blockIdx.x*CC*CC;
  for (int i = threadIdx.x; i < CC*CC; i += 256){
    int k = i >> 7, n = i & 127;
    float f = W[i] * (scale ? lnow[k] : 1.0f);
    t[n*CC + SW16(n, k)] = f2bf(f);
  }
  __syncthreads();
  for (int i = threadIdx.x; i < CC*16; i += 256){
    int n = i >> 4, g = i & 15;
    *(u16x8*)&o[n*CC + g*8] = *(const u16x8*)&t[n*CC + SW16(n, g*8)];
  }
}

// ---------------- k1a: streaming LN(z) -> zng bf16 [pos][k], pre-swizzled SW16 ----------------
__global__ __launch_bounds__(256) void k1a(const float* __restrict__ z,
    const float* __restrict__ lnw, const float* __restrict__ lnb,
    unsigned short* __restrict__ zng)
{
  const int wave = threadIdx.x>>6, lane = threadIdx.x&63;
  const int lh = lane&31, hh = lane>>5;
  const float4 lw4 = *(const float4*)&lnw[4*lh];
  const float4 lb4 = *(const float4*)&lnb[4*lh];
  const int rowbase = blockIdx.x*128 + wave*32;
  for (int it = 0; it < 16; ++it){
    int pos = rowbase + it*2 + hh;
    float4 v = *(const float4*)&z[(size_t)pos*CC + 4*lh];
    float s = v.x+v.y+v.z+v.w;
    float q = v.x*v.x+v.y*v.y+v.z*v.z+v.w*v.w;
    #pragma unroll
    for (int off = 16; off; off >>= 1){ s += __shfl_xor(s, off); q += __shfl_xor(q, off); }
    float mean = s*(1.f/128.f);
    float rstd = rsqrtf(q*(1.f/128.f) - mean*mean + 1e-5f);
    u16x4 o;
    o[0] = f2bf((v.x-mean)*rstd*lw4.x + lb4.x);
    o[1] = f2bf((v.y-mean)*rstd*lw4.y + lb4.y);
    o[2] = f2bf((v.z-mean)*rstd*lw4.z + lb4.z);
    o[3] = f2bf((v.w-mean)*rstd*lw4.w + lb4.w);
    *(u16x4*)&zng[(size_t)pos*CC + ((4*lh) ^ ((pos&15)<<3))] = o;
  }
}

// ---------------- k1b: projections. blockIdx.y: 0=a, 1=b, 2=gate ----------------
__global__ __launch_bounds__(256,3) void k1b(
    const unsigned short* __restrict__ zng, const float* __restrict__ mask,
    const float* __restrict__ bag, const float* __restrict__ bap,
    const float* __restrict__ bbg, const float* __restrict__ bbp,
    const float* __restrict__ bgt, const unsigned short* __restrict__ Wt,
    unsigned short* __restrict__ At, unsigned short* __restrict__ Bt,
    unsigned short* __restrict__ G)
{
  __shared__ unsigned short zn[64*CC];   // 16KB, swizzled content (pre-swizzled in global)
  const int tid = threadIdx.x, wave = tid>>6, lane = tid&63;
  const int l16 = lane&15, lg = lane>>4;
  const int type = blockIdx.y;
  const int tb = blockIdx.x*64;

  { // async 16KB stage: 4 waves x 4 x 1KB, linear
    const char* src = (const char*)(zng + (size_t)tb*CC);
    #pragma unroll
    for (int it = 0; it < 4; ++it){
      int off = (wave*4 + it)*1024;
      gload_lds16(src + off + lane*16, (char*)zn + off);
    }
  }
  __syncthreads();

  if (type < 2){
    // swapped GEMM: D[c][pos] = W[c][k] * zn[pos][k]^T for g and p mats
    const unsigned short* Wg = Wt + (type*2+0)*CC*CC;
    const unsigned short* Wp = Wt + (type*2+1)*CC*CC;
    f32x4 ag[2][4] = {}, ap[2][4] = {};
    #pragma unroll
    for (int kc = 0; kc < 4; ++kc){
      const int kb = kc*32 + lg*8;
      bf16x8 bz[4], wgf[2], wpf[2];
      #pragma unroll
      for (int nb = 0; nb < 4; ++nb){
        int pl = nb*16 + l16;
        bz[nb] = *(const bf16x8*)&zn[pl*CC + (kb ^ (l16<<3))];
      }
      #pragma unroll
      for (int ma = 0; ma < 2; ++ma){
        int c = wave*32 + ma*16 + l16;
        wgf[ma] = *(const bf16x8*)&Wg[c*CC + kb];
        wpf[ma] = *(const bf16x8*)&Wp[c*CC + kb];
      }
      #pragma unroll
      for (int ma = 0; ma < 2; ++ma)
        #pragma unroll
        for (int nb = 0; nb < 4; ++nb){
          ag[ma][nb] = __builtin_amdgcn_mfma_f32_16x16x32_bf16(wgf[ma], bz[nb], ag[ma][nb], 0,0,0);
          ap[ma][nb] = __builtin_amdgcn_mfma_f32_16x16x32_bf16(wpf[ma], bz[nb], ap[ma][nb], 0,0,0);
        }
    }
    const float* Bg_ = type ? bbg : bag;
    const float* Bp_ = type ? bbp : bap;
    unsigned short* dst = type ? Bt : At;
    f32x4 bg4[2], bp4[2];
    #pragma unroll
    for (int ma = 0; ma < 2; ++ma){
      int cb = wave*32 + ma*16 + lg*4;
      bg4[ma] = *(const f32x4*)&Bg_[cb];
      bp4[ma] = *(const f32x4*)&Bp_[cb];
    }
    #pragma unroll
    for (int nb = 0; nb < 4; ++nb){
      int pos = tb + nb*16 + l16;
      float m = mask[pos];
      #pragma unroll
      for (int ma = 0; ma < 2; ++ma){
        int cb = wave*32 + ma*16 + lg*4;
        #pragma unroll
        for (int r = 0; r < 4; ++r){
          float v = m * sigm(ag[ma][nb][r] + bg4[ma][r]) * (ap[ma][nb][r] + bp4[ma][r]);
          dst[(size_t)(cb + r)*NP + pos] = f2bf(v);
        }
      }
    }
  } else {
    // gate: D[pos][c] = zn[pos][k] * WgT[c][k]^T
    const unsigned short* Wgt = Wt + 4*CC*CC;
    f32x4 acc[8] = {};
    #pragma unroll
    for (int kc = 0; kc < 4; ++kc){
      const int kb = kc*32 + lg*8;
      int pl = wave*16 + l16;
      bf16x8 az = *(const bf16x8*)&zn[pl*CC + (kb ^ (l16<<3))];
      bf16x8 wf[8];
      #pragma unroll
      for (int nr = 0; nr < 8; ++nr)
        wf[nr] = *(const bf16x8*)&Wgt[(nr*16+l16)*CC + kb];
      #pragma unroll
      for (int nr = 0; nr < 8; ++nr)
        acc[nr] = __builtin_amdgcn_mfma_f32_16x16x32_bf16(az, wf[nr], acc[nr], 0,0,0);
    }
    #pragma unroll
    for (int nr = 0; nr < 8; ++nr){
      int c = nr*16 + l16;
      float bv = bgt[c];
      #pragma unroll
      for (int r = 0; r < 4; ++r){
        int pos = tb + wave*16 + lg*4 + r;
        G[(size_t)pos*CC + c] = f2bf(sigm(acc[nr][r] + bv));
      }
    }
  }
}

// ---------------- k2: per-channel triangle GEMM  X_c = A_c * B_c^T ----------------
__global__ __launch_bounds__(256) void k2(const unsigned short* __restrict__ At,
                                          const unsigned short* __restrict__ Bt,
                                          unsigned short* __restrict__ Xt)
{
  __shared__ unsigned short As[128*64];   // [row][k] bf16, swizzled
  __shared__ unsigned short Bs[128*64];
  const int c  = blockIdx.y;
  const int ti = blockIdx.x / 3, tj = blockIdx.x % 3;
  const int tid = threadIdx.x, wave = tid >> 6, lane = tid & 63;
  const int l16 = lane & 15, lg = lane >> 4;
  const unsigned short* Ag = At + (size_t)c*NP + (size_t)(ti*128)*NN;
  const unsigned short* Bg = Bt + (size_t)c*NP + (size_t)(tj*128)*NN;
  f32x4 acc[2][8] = {};
  for (int k0 = 0; k0 < NN; k0 += 64){
    __syncthreads();
    #pragma unroll
    for (int it = 0; it < 4; ++it){
      int i = tid + it*256;
      int row = i >> 3, g = i & 7;
      u16x8 va = *(const u16x8*)&Ag[(size_t)row*NN + k0 + g*8];
      u16x8 vb = *(const u16x8*)&Bg[(size_t)row*NN + k0 + g*8];
      *(u16x8*)&As[row*64 + SW8(row, g*8)] = va;
      *(u16x8*)&Bs[row*64 + SW8(row, g*8)] = vb;
    }
    __syncthreads();
    #pragma unroll
    for (int kc = 0; kc < 2; ++kc){
      const int kb = kc*32 + lg*8;
      bf16x8 af[2], bfr[8];
      #pragma unroll
      for (int ma = 0; ma < 2; ++ma){
        int row = wave*32 + ma*16 + l16;
        af[ma] = *(const bf16x8*)&As[row*64 + SW8(row, kb)];
      }
      #pragma unroll
      for (int nr = 0; nr < 8; ++nr){
        int row = nr*16 + l16;
        bfr[nr] = *(const bf16x8*)&Bs[row*64 + SW8(row, kb)];
      }
      #pragma unroll
      for (int ma = 0; ma < 2; ++ma)
        #pragma unroll
        for (int nr = 0; nr < 8; ++nr)
          acc[ma][nr] = __builtin_amdgcn_mfma_f32_16x16x32_bf16(af[ma], bfr[nr], acc[ma][nr], 0,0,0);
    }
  }
  size_t base = (size_t)c*NP + (size_t)(ti*128)*NN + tj*128;
  #pragma unroll
  for (int ma = 0; ma < 2; ++ma)
    #pragma unroll
    for (int nr = 0; nr < 8; ++nr)
      #pragma unroll
      for (int r = 0; r < 4; ++r){
        int row = wave*32 + ma*16 + lg*4 + r;
        int col = nr*16 + l16;
        Xt[base + (size_t)row*NN + col] = f2bf(acc[ma][nr][r]);
      }
}

// ---------------- k3: LN(x)+proj folded: out = (rs*Xw' - rs*mu*wsum + bz')*G ----------------
__global__ __launch_bounds__(256) void k3(const unsigned short* __restrict__ Xt,
    const unsigned short* __restrict__ G,
    const unsigned short* __restrict__ Wzt, const float* __restrict__ wsum,
    const float* __restrict__ bzp, float* __restrict__ out)
{
  __shared__ unsigned short xc[CC*CC];   // [c][pos] bf16, swizzled
  __shared__ float sredS[8*CC], sredQ[8*CC];
  __shared__ float rsl[CC], rml[CC];
  const int tid = threadIdx.x, wave = tid>>6, lane = tid&63;
  const int l16 = lane&15, lg = lane>>4;
  const int posbase = blockIdx.x*128;

  #pragma unroll
  for (int it = 0; it < 8; ++it){
    int i = it*256 + tid;
    int cc = i >> 4, g = i & 15;
    u16x8 v = *(const u16x8*)&Xt[(size_t)cc*NP + posbase + g*8];
    *(u16x8*)&xc[cc*CC + SW16(cc, g*8)] = v;
  }
  __syncthreads();

  { // stats: 256-way parallel (4 pos x 16 channels each), tree-combined
    const int lh = tid & 31;
    const int qq = tid >> 5;
    f32x4 s4 = {0,0,0,0}, q4 = {0,0,0,0};
    #pragma unroll
    for (int ci = 0; ci < 16; ++ci){
      int cc = qq*16 + ci;
      u16x4 v = *(const u16x4*)&xc[cc*CC + ((4*lh) ^ ((cc&15)<<3))];
      #pragma unroll
      for (int j = 0; j < 4; ++j){ float f = bf2f(v[j]); s4[j] += f; q4[j] += f*f; }
    }
    *(f32x4*)&sredS[qq*CC + 4*lh] = s4;
    *(f32x4*)&sredQ[qq*CC + 4*lh] = q4;
  }
  __syncthreads();
  if (tid < 128){
    float s = 0.f, q = 0.f;
    #pragma unroll
    for (int qq = 0; qq < 8; ++qq){ s += sredS[qq*CC + tid]; q += sredQ[qq*CC + tid]; }
    float mean = s*(1.f/128.f);
    float rstd = rsqrtf(q*(1.f/128.f) - mean*mean + 1e-5f);
    rsl[tid] = rstd; rml[tid] = rstd*mean;
  }
  __syncthreads();

  // GEMM on RAW xc (LN folded into Wzt/wsum/bzp)
  f32x4 acc[2][8] = {};
  #pragma unroll
  for (int kc = 0; kc < 4; ++kc){
    const int kb = kc*32 + lg*8;
    bf16x8 af[2];
    #pragma unroll
    for (int ma = 0; ma < 2; ++ma){
      int pos = wave*32 + ma*16 + l16;
      bf16x8 a;
      #pragma unroll
      for (int j = 0; j < 8; ++j){
        int c = kb + j;
        a[j] = (short)xc[c*CC + (pos ^ ((c&15)<<3))];
      }
      af[ma] = a;
    }
    bf16x8 wf[8];
    #pragma unroll
    for (int nr = 0; nr < 8; ++nr)
      wf[nr] = *(const bf16x8*)&Wzt[(nr*16+l16)*CC + kb];
    #pragma unroll
    for (int ma = 0; ma < 2; ++ma)
      #pragma unroll
      for (int nr = 0; nr < 8; ++nr)
        acc[ma][nr] = __builtin_amdgcn_mfma_f32_16x16x32_bf16(af[ma], wf[nr], acc[ma][nr], 0,0,0);
  }

  #pragma unroll
  for (int nr = 0; nr < 8; ++nr){
    int c = nr*16 + l16;
    float wsc = wsum[c], bzc = bzp[c];
    #pragma unroll
    for (int ma = 0; ma < 2; ++ma)
      #pragma unroll
      for (int r = 0; r < 4; ++r){
        int pl = wave*32 + ma*16 + lg*4 + r;
        size_t o = (size_t)(posbase + pl)*CC + c;
        out[o] = (rsl[pl]*acc[ma][nr][r] - rml[pl]*wsc + bzc) * bf2f(G[o]);
      }
  }
}

extern "C" void kernel_launch(void* const* d_in, const int* in_sizes, int n_in,
                              void* d_out, int out_size, void* d_ws, size_t ws_size,
                              hipStream_t stream)
{
  const float* z    = (const float*)d_in[0];
  const float* mask = (const float*)d_in[1];
  const float* lniw = (const float*)d_in[2];
  const float* lnib = (const float*)d_in[3];
  const float* wag  = (const float*)d_in[4];
  const float* bag  = (const float*)d_in[5];
  const float* wap  = (const float*)d_in[6];
  const float* bap  = (const float*)d_in[7];
  const float* wbg  = (const float*)d_in[8];
  const float* bbg  = (const float*)d_in[9];
  const float* wbp  = (const float*)d_in[10];
  const float* bbp  = (const float*)d_in[11];
  const float* lnow = (const float*)d_in[12];
  const float* lnob = (const float*)d_in[13];
  const float* wz   = (const float*)d_in[14];
  const float* bz   = (const float*)d_in[15];
  const float* wg   = (const float*)d_in[16];
  const float* bg   = (const float*)d_in[17];
  float* out = (float*)d_out;

  unsigned short* Wt = (unsigned short*)d_ws;            // 6 x 128x128 bf16 = 192 KB
  float* wsum = (float*)(Wt + 6*CC*CC);                  // 128 f32
  float* bzp  = wsum + CC;                               // 128 f32
  unsigned short* Xt = (unsigned short*)(bzp + CC + 64); // [c][pos]; doubles as zng first
  unsigned short* zng = Xt;                              // alias: zn dead before k2 writes Xt
  unsigned short* At = Xt + (size_t)CC*NP;               // [c][pos]
  unsigned short* Bt = At + (size_t)CC*NP;               // [c][pos]
  unsigned short* G  = Bt + (size_t)CC*NP;               // [pos][c]

  k0<<<7, 256, 0, stream>>>(wag, wap, wbg, wbp, wg, wz, lnow, lnob, bz, Wt, wsum, bzp);
  k1a<<<NP/128, 256, 0, stream>>>(z, lniw, lnib, zng);
  k1b<<<dim3(NP/64, 3), 256, 0, stream>>>(zng, mask, bag, bap, bbg, bbp, bg, Wt, At, Bt, G);
  k2<<<dim3(9, CC), 256, 0, stream>>>(At, Bt, Xt);
  k3<<<NP/128, 256, 0, stream>>>(Xt, G, Wt + 5*CC*CC, wsum, bzp, out);
}